// Round 9
// baseline (509.902 us; speedup 1.0000x reference)
//
#include <hip/hip_runtime.h>
#include <hip/hip_cooperative_groups.h>
#include <math.h>

namespace cg = cooperative_groups;

// 2D IDCT 4096x4096 — single cooperative kernel, 4 phases, 3 grid syncs.
// P0: twiddle/coeff tables (8 vblocks).
// P1: colA — Z-build + 32-pt FFT as in-wave DIT (lane l <-> l+32 = k2
//     parity), register loads (round-4 proven body).
// P2: colB — 64-pt FFT as in-wave DIT over k1, __shfl_xor combine.
// P3: rows — in-place LDS Stockham radix-8/8/8/4, float4 staged I/O.
// Rationale: sum of the 4 separate dispatches ~130us but measured 190us;
// the ~60us constant residual is inter-dispatch overhead -> fuse.

#define TT 256

constexpr float W64R[32] = {
    1.0f, 0.995184726672197f, 0.980785280403230f, 0.956940335732209f,
    0.923879532511287f, 0.881921264348355f, 0.831469612302545f, 0.773010453362737f,
    0.707106781186548f, 0.634393284163645f, 0.555570233019602f, 0.471396736825998f,
    0.382683432365090f, 0.290284677254462f, 0.195090322016128f, 0.0980171403295606f,
    0.0f, -0.0980171403295606f, -0.195090322016128f, -0.290284677254462f,
    -0.382683432365090f, -0.471396736825998f, -0.555570233019602f, -0.634393284163645f,
    -0.707106781186548f, -0.773010453362737f, -0.831469612302545f, -0.881921264348355f,
    -0.923879532511287f, -0.956940335732209f, -0.980785280403230f, -0.995184726672197f};
constexpr float W64I[32] = {
    0.0f, 0.0980171403295606f, 0.195090322016128f, 0.290284677254462f,
    0.382683432365090f, 0.471396736825998f, 0.555570233019602f, 0.634393284163645f,
    0.707106781186548f, 0.773010453362737f, 0.831469612302545f, 0.881921264348355f,
    0.923879532511287f, 0.956940335732209f, 0.980785280403230f, 0.995184726672197f,
    1.0f, 0.995184726672197f, 0.980785280403230f, 0.956940335732209f,
    0.923879532511287f, 0.881921264348355f, 0.831469612302545f, 0.773010453362737f,
    0.707106781186548f, 0.634393284163645f, 0.555570233019602f, 0.471396736825998f,
    0.382683432365090f, 0.290284677254462f, 0.195090322016128f, 0.0980171403295606f};

__device__ __forceinline__ constexpr int brev(int x, int bits) {
    int r = 0;
    for (int i = 0; i < bits; ++i) { r = (r << 1) | (x & 1); x >>= 1; }
    return r;
}

// in-register DIF FFT (sign +), output bit-reversed: re/im[j] = z[brev(j)]
template <int NP>
__device__ __forceinline__ void fft_dif(float* re, float* im) {
#pragma unroll
    for (int h = NP / 2; h >= 1; h >>= 1) {
#pragma unroll
        for (int b = 0; b < NP; b += 2 * h) {
#pragma unroll
            for (int k = 0; k < h; ++k) {
                float ur = re[b + k], ui = im[b + k];
                float vr = re[b + k + h], vi = im[b + k + h];
                float dr = ur - vr, di = ui - vi;
                re[b + k] = ur + vr;
                im[b + k] = ui + vi;
                float wr = W64R[k * (32 / h)], wi = W64I[k * (32 / h)];
                re[b + k + h] = dr * wr - di * wi;
                im[b + k + h] = dr * wi + di * wr;
            }
        }
    }
}

// ---- radix-8 DFT (sign +) --------------------------------------------------
#define C_SQ2 0.70710678118654752440f
__device__ __forceinline__ void radix8(const float* ar, const float* ai,
                                       float* tr, float* ti) {
    float s04r = ar[0] + ar[4], s04i = ai[0] + ai[4];
    float d04r = ar[0] - ar[4], d04i = ai[0] - ai[4];
    float s26r = ar[2] + ar[6], s26i = ai[2] + ai[6];
    float d26r = ar[2] - ar[6], d26i = ai[2] - ai[6];
    float E0r = s04r + s26r, E0i = s04i + s26i;
    float E1r = d04r - d26i, E1i = d04i + d26r;
    float E2r = s04r - s26r, E2i = s04i - s26i;
    float E3r = d04r + d26i, E3i = d04i - d26r;
    float s15r = ar[1] + ar[5], s15i = ai[1] + ai[5];
    float d15r = ar[1] - ar[5], d15i = ai[1] - ai[5];
    float s37r = ar[3] + ar[7], s37i = ai[3] + ai[7];
    float d37r = ar[3] - ar[7], d37i = ai[3] - ai[7];
    float O0r = s15r + s37r, O0i = s15i + s37i;
    float O1r = d15r - d37i, O1i = d15i + d37r;
    float O2r = s15r - s37r, O2i = s15i - s37i;
    float O3r = d15r + d37i, O3i = d15i - d37r;
    float W1r = C_SQ2 * (O1r - O1i), W1i = C_SQ2 * (O1r + O1i);
    float W2r = -O2i, W2i = O2r;
    float W3r = -C_SQ2 * (O3r + O3i), W3i = C_SQ2 * (O3r - O3i);
    tr[0] = E0r + O0r; ti[0] = E0i + O0i;
    tr[4] = E0r - O0r; ti[4] = E0i - O0i;
    tr[1] = E1r + W1r; ti[1] = E1i + W1i;
    tr[5] = E1r - W1r; ti[5] = E1i - W1i;
    tr[2] = E2r + W2r; ti[2] = E2i + W2i;
    tr[6] = E2r - W2r; ti[6] = E2i - W2i;
    tr[3] = E3r + W3r; ti[3] = E3i + W3i;
    tr[7] = E3r - W3r; ti[7] = E3i - W3i;
}

__global__ __launch_bounds__(TT, 4) void idct2_fused(
    const float* __restrict__ x,
    float2* __restrict__ tw2048,
    float2* __restrict__ ca, float2* __restrict__ cb,
    float2* __restrict__ cc, float2* __restrict__ cd,
    float4* __restrict__ cAC,
    float2* __restrict__ T1, float* __restrict__ out) {
    cg::grid_group grid = cg::this_grid();
    const int t = threadIdx.x;
    const int bid = blockIdx.x;
    const int gdim = gridDim.x;
    __shared__ float pool[8576];   // 34304 B -> 4 blocks/CU

    // ================= P0: tables (double precision) =================
    if (bid < 8) {
        int k = bid * TT + t;      // [0, 2048)
        const double s = 0.5 / 4096.0;
        double aw = M_PI * (double)k / 2048.0;
        double wr = cos(aw), wi = sin(aw);
        double a1 = M_PI * (double)k / 8192.0;
        double e1r = cos(a1), e1i = sin(a1);
        double a2 = M_PI * (double)(k + 2048) / 8192.0;
        double e2r = cos(a2), e2i = sin(a2);
        double Ar = s * ((1.0 - wi) * e1r - wr * e1i);
        double Ai = s * ((1.0 - wi) * e1i + wr * e1r);
        double Br = (k == 0) ? 0.0 : Ai;
        double Bi = (k == 0) ? 0.0 : -Ar;
        double Cr = s * ((1.0 + wi) * e2r + wr * e2i);
        double Ci = s * ((1.0 + wi) * e2i - wr * e2r);
        ca[k] = make_float2((float)Ar, (float)Ai);
        cb[k] = make_float2((float)Br, (float)Bi);
        cc[k] = make_float2((float)Cr, (float)Ci);
        cd[k] = make_float2((float)Ci, (float)-Cr);
        cAC[k] = make_float4((float)Ar, (float)Ai, (float)Cr, (float)Ci);
        double at = M_PI * (double)k / 1024.0;
        tw2048[k] = make_float2((float)cos(at), (float)sin(at));
    }
    grid.sync();

    // ================= P1: colA (vgrid 2048 = 128 c-tiles x 16) ========
    // thread: l = t&63 (lane), ty = t>>6; wave = one ty row (x-dim 64
    // equivalent). Lanes l / l+32: same column, even/odd k2 parity.
    for (int vb = bid; vb < 2048; vb += gdim) {
        const int bx = vb & 127, by = vb >> 7;
        const int l = t & 63;
        const int ty = t >> 6;
        const int par = l >> 5;
        const int c = bx * 32 + (l & 31);
        const int k1 = by * 4 + ty;          // [0,64)
        float fr[16], fi[16];
#pragma unroll
        for (int a = 0; a < 16; ++a) {
            int k = k1 + 64 * (2 * a + par);
            float xa = x[(size_t)k * 4096 + c];
            float xb = x[(size_t)((4096 - k) & 4095) * 4096 + c];
            float xc = x[(size_t)(2048 + k) * 4096 + c];
            float xd = x[(size_t)(2048 - k) * 4096 + c];
            float4 P = cAC[k];               // (Ar, Ai, Cr, Ci)
            float bs = (k == 0) ? 0.0f : 1.0f;
            fr[a] = P.x * xa + bs * P.y * xb + P.z * xc + P.w * xd;
            fi[a] = P.y * xa - bs * P.x * xb + P.w * xc - P.z * xd;
        }
        fft_dif<16>(fr, fi);                 // E (par=0) or O (par=1)
        const float sgn = par ? -1.0f : 1.0f;
#pragma unroll
        for (int j = 0; j < 16; ++j) {
            int n = brev(j, 4);
            float wr = par ? W64R[2 * n] : 1.0f;   // W32^n on odd branch
            float wi = par ? W64I[2 * n] : 0.0f;
            float vr = fr[j] * wr - fi[j] * wi;
            float vi = fr[j] * wi + fi[j] * wr;
            float orr = __shfl_xor(vr, 32, 64);
            float oii = __shfl_xor(vi, 32, 64);
            float zr = orr + sgn * vr;       // lower: E+WO ; upper: E-WO
            float zi = oii + sgn * vi;
            int n2 = par ? (n + 16) : n;
            float2 w2 = tw2048[k1 * n2];
            float2 o = make_float2(zr * w2.x - zi * w2.y,
                                   zr * w2.y + zi * w2.x);
            T1[(size_t)(k1 * 32 + n2) * 4096 + c] = o;
        }
    }
    grid.sync();

    // ================= P2: colB (vgrid 1024 = 128 c-tiles x 8) =========
    for (int vb = bid; vb < 1024; vb += gdim) {
        const int bx = vb & 127, by = vb >> 7;
        const int wv = t >> 6;
        const int l = t & 63;
        const int par = l >> 5;
        const int c = bx * 32 + (l & 31);
        const int n2 = by * 4 + wv;
        float fr[32], fi[32];
#pragma unroll
        for (int a = 0; a < 32; ++a) {
            int k1 = 2 * a + par;
            float2 v = T1[(size_t)(k1 * 32 + n2) * 4096 + c];
            fr[a] = v.x; fi[a] = v.y;
        }
        fft_dif<32>(fr, fi);
        const float sgn = par ? -1.0f : 1.0f;
#pragma unroll
        for (int j = 0; j < 32; ++j) {
            int n = brev(j, 5);
            float wr = par ? W64R[n] : 1.0f;
            float wi = par ? W64I[n] : 0.0f;
            float vr = fr[j] * wr - fi[j] * wi;
            float vi = fr[j] * wi + fi[j] * wr;
            float orr = __shfl_xor(vr, 32, 64);
            float oii = __shfl_xor(vi, 32, 64);
            float zr = orr + sgn * vr;
            float zi = oii + sgn * vi;
            int n1 = par ? (n + 32) : n;
            int m = 32 * n1 + n2;
            int r_re = (n1 < 32) ? 4 * m     : 8191 - 4 * m;
            int r_im = (n1 < 32) ? 4 * m + 2 : 8189 - 4 * m;
            out[(size_t)r_re * 4096 + c] = zr;
            out[(size_t)r_im * 4096 + c] = zi;
        }
    }
    grid.sync();

    // ================= P3: rows (vgrid 4096) ===========================
    {
        float* b0r = pool;
        float* b0i = pool + 2112;
        float* b1r = pool + 4224;
        float* b1i = pool + 6400;
        float* stg = pool + 4224;   // overlays b1 (free until stage B)
        for (int vb = bid; vb < 4096; vb += gdim) {
            float* __restrict__ xr = out + (size_t)vb * 4096;
            // stage the row via float4 loads
#pragma unroll
            for (int u = 0; u < 4; ++u) {
                int idx = t + 256 * u;
                float4 v = ((const float4*)xr)[idx];
                *(float4*)&stg[4 * idx] = v;
            }
            __syncthreads();
            float zr[8], zi[8], tr[8], ti[8];
#pragma unroll
            for (int p = 0; p < 8; ++p) {
                int k = t + 256 * p;
                float xa = stg[k];
                float xb = stg[(4096 - k) & 4095];
                float xc = stg[2048 + k];
                float xd = stg[2048 - k];
                float2 A = ca[k], B = cb[k], C = cc[k], D = cd[k];
                zr[p] = A.x * xa + B.x * xb + C.x * xc + D.x * xd;
                zi[p] = A.y * xa + B.y * xb + C.y * xc + D.y * xd;
            }
            // stage A: m=1
            radix8(zr, zi, tr, ti);
            {
                int baseA = 8 * t + (t >> 2);
                b0r[baseA] = tr[0]; b0i[baseA] = ti[0];
#pragma unroll
                for (int q = 1; q < 8; ++q) {
                    float2 w = tw2048[(t * q) & 2047];
                    b0r[baseA + q] = w.x * tr[q] - w.y * ti[q];
                    b0i[baseA + q] = w.x * ti[q] + w.y * tr[q];
                }
            }
            __syncthreads();
            // stage B: m=8
            {
                float ar[8], ai[8];
                int rb = t + (t >> 5);
#pragma unroll
                for (int p = 0; p < 8; ++p) { ar[p] = b0r[rb + 264 * p]; ai[p] = b0i[rb + 264 * p]; }
                radix8(ar, ai, tr, ti);
                int j = t >> 3, k = t & 7, wj = 8 * j;
                int baseB = 68 * j + k;
                b1r[baseB] = tr[0]; b1i[baseB] = ti[0];
#pragma unroll
                for (int q = 1; q < 8; ++q) {
                    int off = baseB + 8 * q + (q >> 1);
                    float2 w = tw2048[(wj * q) & 2047];
                    b1r[off] = w.x * tr[q] - w.y * ti[q];
                    b1i[off] = w.x * ti[q] + w.y * tr[q];
                }
            }
            __syncthreads();
            // stage C: m=64
            {
                float ar[8], ai[8];
                int rb = t + (t >> 4);
#pragma unroll
                for (int p = 0; p < 8; ++p) { ar[p] = b1r[rb + 272 * p]; ai[p] = b1i[rb + 272 * p]; }
                radix8(ar, ai, tr, ti);
                int j = t >> 6, wj = 64 * j, k = t & 63;
                int baseC = 528 * j + k + (k >> 5);
                b0r[baseC] = tr[0]; b0i[baseC] = ti[0];
#pragma unroll
                for (int q = 1; q < 8; ++q) {
                    int off = baseC + 66 * q;
                    float2 w = tw2048[(wj * q) & 2047];
                    b0r[off] = w.x * tr[q] - w.y * ti[q];
                    b0i[off] = w.x * ti[q] + w.y * tr[q];
                }
            }
            __syncthreads();
            // stage D: m=512 radix-4, tw=1
#pragma unroll
            for (int u = 0; u < 2; ++u) {
                int b = t + 256 * u;
                int rb = b + (b >> 5);
                int wb = b + (b >> 4);
                float a0r = b0r[rb], a0i = b0i[rb];
                float a1r = b0r[rb + 528], a1i = b0i[rb + 528];
                float a2r = b0r[rb + 1056], a2i = b0i[rb + 1056];
                float a3r = b0r[rb + 1584], a3i = b0i[rb + 1584];
                float s02r = a0r + a2r, s02i = a0i + a2i;
                float d02r = a0r - a2r, d02i = a0i - a2i;
                float s13r = a1r + a3r, s13i = a1i + a3i;
                float d13r = a1r - a3r, d13i = a1i - a3i;
                b1r[wb] = s02r + s13r;          b1i[wb] = s02i + s13i;
                b1r[wb + 544] = d02r - d13i;    b1i[wb + 544] = d02i + d13r;
                b1r[wb + 1088] = s02r - s13r;   b1i[wb + 1088] = s02i - s13i;
                b1r[wb + 1632] = d02r + d13i;   b1i[wb + 1632] = d02i - d13r;
            }
            __syncthreads();
            // epilogue
#pragma unroll
            for (int i = 0; i < 4; ++i) {
                int s = t + 256 * i;
                int l2 = 2047 - s;
                int ms = s + (s >> 4);
                int ml = l2 + (l2 >> 4);
                float4 o = make_float4(b1r[ms], b1i[ml], b1i[ms], b1r[ml]);
                *(float4*)&xr[4 * s] = o;
            }
            __syncthreads();   // pool (b1) reused as stg next iteration
        }
    }
}

extern "C" void kernel_launch(void* const* d_in, const int* in_sizes, int n_in,
                              void* d_out, int out_size, void* d_ws, size_t ws_size,
                              hipStream_t stream) {
    const float* x = (const float*)d_in[0];
    float* out = (float*)d_out;

    float2* tw2048 = (float2*)d_ws;
    float2* ca = (float2*)((char*)d_ws + 1 * 16384);
    float2* cb = (float2*)((char*)d_ws + 2 * 16384);
    float2* cc = (float2*)((char*)d_ws + 3 * 16384);
    float2* cd = (float2*)((char*)d_ws + 4 * 16384);
    float4* cAC = (float4*)((char*)d_ws + 5 * 16384);   // 32 KB
    float2* T1 = (float2*)((char*)d_ws + (1 << 20));    // 64 MB

    // capacity-validated cooperative grid (host-side query; no allocation)
    int occ = 0;
    hipOccupancyMaxActiveBlocksPerMultiprocessor(&occ, idct2_fused, TT, 0);
    if (occ < 1) occ = 1;
    int ncu = 0;
    if (hipDeviceGetAttribute(&ncu, hipDeviceAttributeMultiprocessorCount, 0)
            != hipSuccess || ncu <= 0)
        ncu = 256;
    int blocks = occ * ncu;
    if (blocks > 1024) blocks = 1024;

    void* args[] = {(void*)&x, (void*)&tw2048, (void*)&ca, (void*)&cb,
                    (void*)&cc, (void*)&cd, (void*)&cAC, (void*)&T1,
                    (void*)&out};
    hipLaunchCooperativeKernel(idct2_fused, dim3(blocks), dim3(TT),
                               args, 0, stream);
}

// Round 11
// 186.657 us; speedup vs baseline: 2.7318x; 2.7318x over previous
//
#include <hip/hip_runtime.h>
#include <hip/hip_cooperative_groups.h>
#include <math.h>

namespace cg = cooperative_groups;

// 2D IDCT 4096x4096 — fused cooperative kernel (4 phases, 3 grid syncs)
// with a four-kernel fallback sharing the same __device__ phase bodies.
// Fused kernel: amdgpu_waves_per_eu(4,4) — max=4 stops the compiler from
// squeezing to 64 VGPR/8-wave (round-9 spill catastrophe), min=4 caps at
// 128 VGPR (> P2's ~104 live set) -> guaranteed 4 blocks/CU, the exact
// 1024-block config that launched and passed in round 9.
// Host falls back to separate kernels if cooperative launch is refused
// (round-10 failure mode: launch silently never ran -> zeros).

#define TT 256

constexpr float W64R[32] = {
    1.0f, 0.995184726672197f, 0.980785280403230f, 0.956940335732209f,
    0.923879532511287f, 0.881921264348355f, 0.831469612302545f, 0.773010453362737f,
    0.707106781186548f, 0.634393284163645f, 0.555570233019602f, 0.471396736825998f,
    0.382683432365090f, 0.290284677254462f, 0.195090322016128f, 0.0980171403295606f,
    0.0f, -0.0980171403295606f, -0.195090322016128f, -0.290284677254462f,
    -0.382683432365090f, -0.471396736825998f, -0.555570233019602f, -0.634393284163645f,
    -0.707106781186548f, -0.773010453362737f, -0.831469612302545f, -0.881921264348355f,
    -0.923879532511287f, -0.956940335732209f, -0.980785280403230f, -0.995184726672197f};
constexpr float W64I[32] = {
    0.0f, 0.0980171403295606f, 0.195090322016128f, 0.290284677254462f,
    0.382683432365090f, 0.471396736825998f, 0.555570233019602f, 0.634393284163645f,
    0.707106781186548f, 0.773010453362737f, 0.831469612302545f, 0.881921264348355f,
    0.923879532511287f, 0.956940335732209f, 0.980785280403230f, 0.995184726672197f,
    1.0f, 0.995184726672197f, 0.980785280403230f, 0.956940335732209f,
    0.923879532511287f, 0.881921264348355f, 0.831469612302545f, 0.773010453362737f,
    0.707106781186548f, 0.634393284163645f, 0.555570233019602f, 0.471396736825998f,
    0.382683432365090f, 0.290284677254462f, 0.195090322016128f, 0.0980171403295606f};

__device__ __forceinline__ constexpr int brev(int x, int bits) {
    int r = 0;
    for (int i = 0; i < bits; ++i) { r = (r << 1) | (x & 1); x >>= 1; }
    return r;
}

template <int NP>
__device__ __forceinline__ void fft_dif(float* re, float* im) {
#pragma unroll
    for (int h = NP / 2; h >= 1; h >>= 1) {
#pragma unroll
        for (int b = 0; b < NP; b += 2 * h) {
#pragma unroll
            for (int k = 0; k < h; ++k) {
                float ur = re[b + k], ui = im[b + k];
                float vr = re[b + k + h], vi = im[b + k + h];
                float dr = ur - vr, di = ui - vi;
                re[b + k] = ur + vr;
                im[b + k] = ui + vi;
                float wr = W64R[k * (32 / h)], wi = W64I[k * (32 / h)];
                re[b + k + h] = dr * wr - di * wi;
                im[b + k + h] = dr * wi + di * wr;
            }
        }
    }
}

#define C_SQ2 0.70710678118654752440f
__device__ __forceinline__ void radix8(const float* ar, const float* ai,
                                       float* tr, float* ti) {
    float s04r = ar[0] + ar[4], s04i = ai[0] + ai[4];
    float d04r = ar[0] - ar[4], d04i = ai[0] - ai[4];
    float s26r = ar[2] + ar[6], s26i = ai[2] + ai[6];
    float d26r = ar[2] - ar[6], d26i = ai[2] - ai[6];
    float E0r = s04r + s26r, E0i = s04i + s26i;
    float E1r = d04r - d26i, E1i = d04i + d26r;
    float E2r = s04r - s26r, E2i = s04i - s26i;
    float E3r = d04r + d26i, E3i = d04i - d26r;
    float s15r = ar[1] + ar[5], s15i = ai[1] + ai[5];
    float d15r = ar[1] - ar[5], d15i = ai[1] - ai[5];
    float s37r = ar[3] + ar[7], s37i = ai[3] + ai[7];
    float d37r = ar[3] - ar[7], d37i = ai[3] - ai[7];
    float O0r = s15r + s37r, O0i = s15i + s37i;
    float O1r = d15r - d37i, O1i = d15i + d37r;
    float O2r = s15r - s37r, O2i = s15i - s37i;
    float O3r = d15r + d37i, O3i = d15i - d37r;
    float W1r = C_SQ2 * (O1r - O1i), W1i = C_SQ2 * (O1r + O1i);
    float W2r = -O2i, W2i = O2r;
    float W3r = -C_SQ2 * (O3r + O3i), W3i = C_SQ2 * (O3r - O3i);
    tr[0] = E0r + O0r; ti[0] = E0i + O0i;
    tr[4] = E0r - O0r; ti[4] = E0i - O0i;
    tr[1] = E1r + W1r; ti[1] = E1i + W1i;
    tr[5] = E1r - W1r; ti[5] = E1i - W1i;
    tr[2] = E2r + W2r; ti[2] = E2i + W2i;
    tr[6] = E2r - W2r; ti[6] = E2i - W2i;
    tr[3] = E3r + W3r; ti[3] = E3i + W3i;
    tr[7] = E3r - W3r; ti[7] = E3i - W3i;
}

// ---------------- phase bodies (shared fused / separate) -------------------
__device__ __forceinline__ void phase_tables(
    int k, float2* __restrict__ tw2048,
    float2* __restrict__ ca, float2* __restrict__ cb,
    float2* __restrict__ cc, float2* __restrict__ cd,
    float4* __restrict__ cAC) {
    const double s = 0.5 / 4096.0;
    double aw = M_PI * (double)k / 2048.0;
    double wr = cos(aw), wi = sin(aw);
    double a1 = M_PI * (double)k / 8192.0;
    double e1r = cos(a1), e1i = sin(a1);
    double a2 = M_PI * (double)(k + 2048) / 8192.0;
    double e2r = cos(a2), e2i = sin(a2);
    double Ar = s * ((1.0 - wi) * e1r - wr * e1i);
    double Ai = s * ((1.0 - wi) * e1i + wr * e1r);
    double Br = (k == 0) ? 0.0 : Ai;
    double Bi = (k == 0) ? 0.0 : -Ar;
    double Cr = s * ((1.0 + wi) * e2r + wr * e2i);
    double Ci = s * ((1.0 + wi) * e2i - wr * e2r);
    ca[k] = make_float2((float)Ar, (float)Ai);
    cb[k] = make_float2((float)Br, (float)Bi);
    cc[k] = make_float2((float)Cr, (float)Ci);
    cd[k] = make_float2((float)Ci, (float)-Cr);
    cAC[k] = make_float4((float)Ar, (float)Ai, (float)Cr, (float)Ci);
    double at = M_PI * (double)k / 1024.0;
    tw2048[k] = make_float2((float)cos(at), (float)sin(at));
}

__device__ __forceinline__ void phase_colA(
    int vb, int t, const float* __restrict__ x,
    const float4* __restrict__ cAC, const float2* __restrict__ tw2048,
    float2* __restrict__ T1) {
    const int bx = vb & 127, by = vb >> 7;
    const int l = t & 63;
    const int ty = t >> 6;
    const int par = l >> 5;
    const int c = bx * 32 + (l & 31);
    const int k1 = by * 4 + ty;              // [0,64)
    float fr[16], fi[16];
#pragma unroll
    for (int a = 0; a < 16; ++a) {
        int k = k1 + 64 * (2 * a + par);
        float xa = x[(size_t)k * 4096 + c];
        float xb = x[(size_t)((4096 - k) & 4095) * 4096 + c];
        float xc = x[(size_t)(2048 + k) * 4096 + c];
        float xd = x[(size_t)(2048 - k) * 4096 + c];
        float4 P = cAC[k];                   // (Ar, Ai, Cr, Ci)
        float bs = (k == 0) ? 0.0f : 1.0f;
        fr[a] = P.x * xa + bs * P.y * xb + P.z * xc + P.w * xd;
        fi[a] = P.y * xa - bs * P.x * xb + P.w * xc - P.z * xd;
    }
    fft_dif<16>(fr, fi);                     // E (par=0) or O (par=1)
    const float sgn = par ? -1.0f : 1.0f;
#pragma unroll
    for (int j = 0; j < 16; ++j) {
        int n = brev(j, 4);
        float wr = par ? W64R[2 * n] : 1.0f; // W32^n on odd branch
        float wi = par ? W64I[2 * n] : 0.0f;
        float vr = fr[j] * wr - fi[j] * wi;
        float vi = fr[j] * wi + fi[j] * wr;
        float orr = __shfl_xor(vr, 32, 64);
        float oii = __shfl_xor(vi, 32, 64);
        float zr = orr + sgn * vr;           // lower: E+WO ; upper: E-WO
        float zi = oii + sgn * vi;
        int n2 = par ? (n + 16) : n;
        float2 w2 = tw2048[k1 * n2];
        float2 o = make_float2(zr * w2.x - zi * w2.y,
                               zr * w2.y + zi * w2.x);
        T1[(size_t)(k1 * 32 + n2) * 4096 + c] = o;
    }
}

__device__ __forceinline__ void phase_colB(
    int vb, int t, const float2* __restrict__ T1, float* __restrict__ out) {
    const int bx = vb & 127, by = vb >> 7;
    const int wv = t >> 6;
    const int l = t & 63;
    const int par = l >> 5;
    const int c = bx * 32 + (l & 31);
    const int n2 = by * 4 + wv;
    float fr[32], fi[32];
#pragma unroll
    for (int a = 0; a < 32; ++a) {
        int k1 = 2 * a + par;
        float2 v = T1[(size_t)(k1 * 32 + n2) * 4096 + c];
        fr[a] = v.x; fi[a] = v.y;
    }
    fft_dif<32>(fr, fi);
    const float sgn = par ? -1.0f : 1.0f;
#pragma unroll
    for (int j = 0; j < 32; ++j) {
        int n = brev(j, 5);
        float wr = par ? W64R[n] : 1.0f;
        float wi = par ? W64I[n] : 0.0f;
        float vr = fr[j] * wr - fi[j] * wi;
        float vi = fr[j] * wi + fi[j] * wr;
        float orr = __shfl_xor(vr, 32, 64);
        float oii = __shfl_xor(vi, 32, 64);
        float zr = orr + sgn * vr;
        float zi = oii + sgn * vi;
        int n1 = par ? (n + 32) : n;
        int m = 32 * n1 + n2;
        int r_re = (n1 < 32) ? 4 * m     : 8191 - 4 * m;
        int r_im = (n1 < 32) ? 4 * m + 2 : 8189 - 4 * m;
        out[(size_t)r_re * 4096 + c] = zr;
        out[(size_t)r_im * 4096 + c] = zi;
    }
}

__device__ __forceinline__ void phase_rows(
    int vb, int t, float* pool,
    const float2* __restrict__ ca, const float2* __restrict__ cb,
    const float2* __restrict__ cc, const float2* __restrict__ cd,
    const float2* __restrict__ tw2048, float* __restrict__ out) {
    float* b0r = pool;
    float* b0i = pool + 2112;
    float* b1r = pool + 4224;
    float* b1i = pool + 6400;
    float* stg = pool + 4224;   // overlays b1 (free until stage B)
    float* __restrict__ xr = out + (size_t)vb * 4096;
#pragma unroll
    for (int u = 0; u < 4; ++u) {
        int idx = t + 256 * u;
        float4 v = ((const float4*)xr)[idx];
        *(float4*)&stg[4 * idx] = v;
    }
    __syncthreads();
    float zr[8], zi[8], tr[8], ti[8];
#pragma unroll
    for (int p = 0; p < 8; ++p) {
        int k = t + 256 * p;
        float xa = stg[k];
        float xb = stg[(4096 - k) & 4095];
        float xc = stg[2048 + k];
        float xd = stg[2048 - k];
        float2 A = ca[k], B = cb[k], C = cc[k], D = cd[k];
        zr[p] = A.x * xa + B.x * xb + C.x * xc + D.x * xd;
        zi[p] = A.y * xa + B.y * xb + C.y * xc + D.y * xd;
    }
    radix8(zr, zi, tr, ti);
    {
        int baseA = 8 * t + (t >> 2);
        b0r[baseA] = tr[0]; b0i[baseA] = ti[0];
#pragma unroll
        for (int q = 1; q < 8; ++q) {
            float2 w = tw2048[(t * q) & 2047];
            b0r[baseA + q] = w.x * tr[q] - w.y * ti[q];
            b0i[baseA + q] = w.x * ti[q] + w.y * tr[q];
        }
    }
    __syncthreads();
    {
        float ar[8], ai[8];
        int rb = t + (t >> 5);
#pragma unroll
        for (int p = 0; p < 8; ++p) { ar[p] = b0r[rb + 264 * p]; ai[p] = b0i[rb + 264 * p]; }
        radix8(ar, ai, tr, ti);
        int j = t >> 3, k = t & 7, wj = 8 * j;
        int baseB = 68 * j + k;
        b1r[baseB] = tr[0]; b1i[baseB] = ti[0];
#pragma unroll
        for (int q = 1; q < 8; ++q) {
            int off = baseB + 8 * q + (q >> 1);
            float2 w = tw2048[(wj * q) & 2047];
            b1r[off] = w.x * tr[q] - w.y * ti[q];
            b1i[off] = w.x * ti[q] + w.y * tr[q];
        }
    }
    __syncthreads();
    {
        float ar[8], ai[8];
        int rb = t + (t >> 4);
#pragma unroll
        for (int p = 0; p < 8; ++p) { ar[p] = b1r[rb + 272 * p]; ai[p] = b1i[rb + 272 * p]; }
        radix8(ar, ai, tr, ti);
        int j = t >> 6, wj = 64 * j, k = t & 63;
        int baseC = 528 * j + k + (k >> 5);
        b0r[baseC] = tr[0]; b0i[baseC] = ti[0];
#pragma unroll
        for (int q = 1; q < 8; ++q) {
            int off = baseC + 66 * q;
            float2 w = tw2048[(wj * q) & 2047];
            b0r[off] = w.x * tr[q] - w.y * ti[q];
            b0i[off] = w.x * ti[q] + w.y * tr[q];
        }
    }
    __syncthreads();
#pragma unroll
    for (int u = 0; u < 2; ++u) {
        int b = t + 256 * u;
        int rb = b + (b >> 5);
        int wb = b + (b >> 4);
        float a0r = b0r[rb], a0i = b0i[rb];
        float a1r = b0r[rb + 528], a1i = b0i[rb + 528];
        float a2r = b0r[rb + 1056], a2i = b0i[rb + 1056];
        float a3r = b0r[rb + 1584], a3i = b0i[rb + 1584];
        float s02r = a0r + a2r, s02i = a0i + a2i;
        float d02r = a0r - a2r, d02i = a0i - a2i;
        float s13r = a1r + a3r, s13i = a1i + a3i;
        float d13r = a1r - a3r, d13i = a1i - a3i;
        b1r[wb] = s02r + s13r;          b1i[wb] = s02i + s13i;
        b1r[wb + 544] = d02r - d13i;    b1i[wb + 544] = d02i + d13r;
        b1r[wb + 1088] = s02r - s13r;   b1i[wb + 1088] = s02i - s13i;
        b1r[wb + 1632] = d02r + d13i;   b1i[wb + 1632] = d02i - d13r;
    }
    __syncthreads();
#pragma unroll
    for (int i = 0; i < 4; ++i) {
        int s = t + 256 * i;
        int l2 = 2047 - s;
        int ms = s + (s >> 4);
        int ml = l2 + (l2 >> 4);
        float4 o = make_float4(b1r[ms], b1i[ml], b1i[ms], b1r[ml]);
        *(float4*)&xr[4 * s] = o;
    }
    __syncthreads();   // pool (b1) reused as stg next iteration
}

// ---------------- fused cooperative kernel ---------------------------------
__global__ __launch_bounds__(TT)
__attribute__((amdgpu_waves_per_eu(4, 4)))
void idct2_fused(
    const float* __restrict__ x,
    float2* __restrict__ tw2048,
    float2* __restrict__ ca, float2* __restrict__ cb,
    float2* __restrict__ cc, float2* __restrict__ cd,
    float4* __restrict__ cAC,
    float2* __restrict__ T1, float* __restrict__ out) {
    cg::grid_group grid = cg::this_grid();
    const int t = threadIdx.x;
    const int bid = blockIdx.x;
    const int gdim = gridDim.x;
    __shared__ float pool[8576];   // 34304 B -> 4 blocks/CU

    if (bid < 8) phase_tables(bid * TT + t, tw2048, ca, cb, cc, cd, cAC);
    grid.sync();

    for (int vb = bid; vb < 2048; vb += gdim)
        phase_colA(vb, t, x, cAC, tw2048, T1);
    grid.sync();

    for (int vb = bid; vb < 1024; vb += gdim)
        phase_colB(vb, t, T1, out);
    grid.sync();

    for (int vb = bid; vb < 4096; vb += gdim)
        phase_rows(vb, t, pool, ca, cb, cc, cd, tw2048, out);
}

// ---------------- separate-kernel fallback ---------------------------------
__global__ void tw_init_sep(float2* __restrict__ tw2048,
                            float2* __restrict__ ca, float2* __restrict__ cb,
                            float2* __restrict__ cc, float2* __restrict__ cd,
                            float4* __restrict__ cAC) {
    phase_tables(blockIdx.x * TT + threadIdx.x, tw2048, ca, cb, cc, cd, cAC);
}

__global__ __launch_bounds__(TT) void col_a_sep(
    const float* __restrict__ x, const float4* __restrict__ cAC,
    const float2* __restrict__ tw2048, float2* __restrict__ T1) {
    phase_colA(blockIdx.x, threadIdx.x, x, cAC, tw2048, T1);
}

__global__ __launch_bounds__(TT, 1) void col_b_sep(
    const float2* __restrict__ T1, float* __restrict__ out) {
    phase_colB(blockIdx.x, threadIdx.x, T1, out);
}

__global__ __launch_bounds__(TT) void rows_sep(
    const float2* __restrict__ ca, const float2* __restrict__ cb,
    const float2* __restrict__ cc, const float2* __restrict__ cd,
    const float2* __restrict__ tw2048, float* __restrict__ out) {
    __shared__ float pool[8576];
    phase_rows(blockIdx.x, threadIdx.x, pool, ca, cb, cc, cd, tw2048, out);
}

extern "C" void kernel_launch(void* const* d_in, const int* in_sizes, int n_in,
                              void* d_out, int out_size, void* d_ws, size_t ws_size,
                              hipStream_t stream) {
    const float* x = (const float*)d_in[0];
    float* out = (float*)d_out;

    float2* tw2048 = (float2*)d_ws;
    float2* ca = (float2*)((char*)d_ws + 1 * 16384);
    float2* cb = (float2*)((char*)d_ws + 2 * 16384);
    float2* cc = (float2*)((char*)d_ws + 3 * 16384);
    float2* cd = (float2*)((char*)d_ws + 4 * 16384);
    float4* cAC = (float4*)((char*)d_ws + 5 * 16384);   // 32 KB
    float2* T1 = (float2*)((char*)d_ws + (1 << 20));    // 64 MB

    // Try fused cooperative launch at the proven 1024-block config; the
    // waves_per_eu(4,4) attribute guarantees VGPR<=128 -> 4 blocks/CU.
    int occ = 0;
    hipError_t qerr =
        hipOccupancyMaxActiveBlocksPerMultiprocessor(&occ, idct2_fused, TT, 0);
    bool coop = (qerr == hipSuccess && occ >= 4);
    if (coop) {
        void* args[] = {(void*)&x, (void*)&tw2048, (void*)&ca, (void*)&cb,
                        (void*)&cc, (void*)&cd, (void*)&cAC, (void*)&T1,
                        (void*)&out};
        hipError_t lerr = hipLaunchCooperativeKernel(
            idct2_fused, dim3(1024), dim3(TT), args, 0, stream);
        if (lerr != hipSuccess) coop = false;
    }
    if (!coop) {
        // proven round-6 four-kernel path (~190 us)
        tw_init_sep<<<8, TT, 0, stream>>>(tw2048, ca, cb, cc, cd, cAC);
        col_a_sep<<<2048, TT, 0, stream>>>(x, cAC, tw2048, T1);
        col_b_sep<<<1024, TT, 0, stream>>>(T1, out);
        rows_sep<<<4096, TT, 0, stream>>>(ca, cb, cc, cd, tw2048, out);
    }
}